// Round 7
// baseline (176.409 us; speedup 1.0000x reference)
//
#include <hip/hip_runtime.h>
#include <hip/hip_bf16.h>
#include <cstdint>

using bf16x8 = __attribute__((ext_vector_type(8))) __bf16;
using f32x4  = __attribute__((ext_vector_type(4))) float;

#define LOG2E 1.4426950408889634f

__device__ inline void gload16(__bf16* lds, const __bf16* g) {
    __builtin_amdgcn_global_load_lds((const __attribute__((address_space(1))) void*)g,
                                     (__attribute__((address_space(3))) void*)lds, 16, 0, 0);
}

// ---------------------------------------------------------------------------
// RMSNorm: one block (256 threads) per row of 1024 fp32 -> bf16
// ---------------------------------------------------------------------------
__global__ __launch_bounds__(256) void rmsnorm_kernel(const float* __restrict__ x,
                                                      const float* __restrict__ w,
                                                      __bf16* __restrict__ xn) {
    const int row = blockIdx.x;
    const float4 v = reinterpret_cast<const float4*>(x + (size_t)row * 1024)[threadIdx.x];
    float ss = v.x * v.x + v.y * v.y + v.z * v.z + v.w * v.w;
#pragma unroll
    for (int i = 1; i < 64; i <<= 1) ss += __shfl_xor(ss, i);
    __shared__ float part[4];
    if ((threadIdx.x & 63) == 0) part[threadIdx.x >> 6] = ss;
    __syncthreads();
    const float total = part[0] + part[1] + part[2] + part[3];
    const float scale = rsqrtf(total * (1.0f / 1024.0f) + 1.1920929e-07f);
    const float4 wv = reinterpret_cast<const float4*>(w)[threadIdx.x];
    union { __bf16 h[4]; uint2 u; } pk;
    pk.h[0] = (__bf16)(v.x * scale * wv.x);
    pk.h[1] = (__bf16)(v.y * scale * wv.y);
    pk.h[2] = (__bf16)(v.z * scale * wv.z);
    pk.h[3] = (__bf16)(v.w * scale * wv.w);
    reinterpret_cast<uint2*>(xn + (size_t)row * 1024)[threadIdx.x] = pk.u;
}

// ---------------------------------------------------------------------------
// Transpose + cast: in (K x N) fp32 row-major -> out (N x K) bf16 row-major
// ---------------------------------------------------------------------------
__global__ void transpose_cast_kernel(const float* __restrict__ in,
                                      __bf16* __restrict__ out, int K, int N) {
    __shared__ float tile[32][33];
    const int n0 = blockIdx.x * 32, k0 = blockIdx.y * 32;
#pragma unroll
    for (int r = threadIdx.y; r < 32; r += 8)
        tile[r][threadIdx.x] = in[(size_t)(k0 + r) * N + n0 + threadIdx.x];
    __syncthreads();
#pragma unroll
    for (int r = threadIdx.y; r < 32; r += 8)
        out[(size_t)(n0 + r) * K + k0 + threadIdx.x] = (__bf16)tile[threadIdx.x][r];
}

// ---------------------------------------------------------------------------
// cos/sin table: csin[pos*64+d] = (cos, sin) of rot[pos][d]. 262144 entries.
// ---------------------------------------------------------------------------
__global__ __launch_bounds__(256) void csin_kernel(const float* __restrict__ rot,
                                                   float2* __restrict__ csin) {
    const int i = blockIdx.x * 256 + threadIdx.x;
    float s, c;
    sincosf(rot[i], &s, &c);
    csin[i] = make_float2(c, s);
}

// ---------------------------------------------------------------------------
// GEMM: C(MxN) = A(MxK) @ Bt(NxK)^T, bf16 in, fp32 accum.
// 128x128 tile, BK=32, 4 waves, global_load_lds width-16 staging.
// ROPE=true (QKV): columns <512 = q (rope+scale), <1024 = k (rope), else v.
// Rope pairs (d, d+32) live in acc[m][nn], acc[m][nn+2] of the same lane.
// ---------------------------------------------------------------------------
template <typename OutT, bool ROPE>
__global__ __launch_bounds__(256) void gemm_bt(const __bf16* __restrict__ A,
                                               const __bf16* __restrict__ Bt,
                                               OutT* __restrict__ C,
                                               int M, int N, int K,
                                               const float2* __restrict__ csin) {
    __shared__ __align__(16) __bf16 As[128 * 32];
    __shared__ __align__(16) __bf16 Bs[128 * 32];
    const int bm = blockIdx.y, bn = blockIdx.x;
    const int tid = threadIdx.x;
    const int w = tid >> 6, l = tid & 63, lg = l >> 4, lr = l & 15;
    const int wr = w >> 1, wc = w & 1;
    const __bf16* Ab = A + (size_t)(bm * 128) * K;
    const __bf16* Bb = Bt + (size_t)(bn * 128) * K;
    const int srow = tid >> 2, scol = (tid & 3) * 8;
    f32x4 acc[4][4] = {};
    for (int k0 = 0; k0 < K; k0 += 32) {
        gload16(As + tid * 8,        Ab + (size_t)srow * K + k0 + scol);
        gload16(As + 2048 + tid * 8, Ab + (size_t)(srow + 64) * K + k0 + scol);
        gload16(Bs + tid * 8,        Bb + (size_t)srow * K + k0 + scol);
        gload16(Bs + 2048 + tid * 8, Bb + (size_t)(srow + 64) * K + k0 + scol);
        __syncthreads();
        bf16x8 af[4], bfr[4];
#pragma unroll
        for (int m = 0; m < 4; ++m)
            af[m] = *reinterpret_cast<const bf16x8*>(&As[(wr * 64 + m * 16 + lr) * 32 + lg * 8]);
#pragma unroll
        for (int nn = 0; nn < 4; ++nn)
            bfr[nn] = *reinterpret_cast<const bf16x8*>(&Bs[(wc * 64 + nn * 16 + lr) * 32 + lg * 8]);
#pragma unroll
        for (int m = 0; m < 4; ++m)
#pragma unroll
            for (int nn = 0; nn < 4; ++nn)
                acc[m][nn] = __builtin_amdgcn_mfma_f32_16x16x32_bf16(af[m], bfr[nn],
                                                                     acc[m][nn], 0, 0, 0);
        __syncthreads();
    }
    if constexpr (ROPE) {
        const int cb = bn * 128 + wc * 64;            // head-aligned column base
        if (cb < 1024) {                              // q or k: apply rope
            const float qs = (cb < 512) ? 0.125f * LOG2E : 1.0f;
#pragma unroll
            for (int m = 0; m < 4; ++m) {
                const int rg = bm * 128 + wr * 64 + m * 16 + 4 * lg;
#pragma unroll
                for (int nn = 0; nn < 2; ++nn) {
                    const int d = nn * 16 + lr;       // 0..31
                    const int cg = cb + d;
#pragma unroll
                    for (int r = 0; r < 4; ++r) {
                        const int row = rg + r;
                        const int pos = row & 4095;
                        const float2 cs  = csin[pos * 64 + d];
                        const float2 cs2 = csin[pos * 64 + d + 32];
                        const float a  = acc[m][nn][r];
                        const float b2 = acc[m][nn + 2][r];
                        C[(size_t)row * N + cg]      = (OutT)((a * cs.x - b2 * cs.y) * qs);
                        C[(size_t)row * N + cg + 32] = (OutT)((b2 * cs2.x + a * cs2.y) * qs);
                    }
                }
            }
            return;
        }
    }
#pragma unroll
    for (int m = 0; m < 4; ++m) {
        const int rg = bm * 128 + wr * 64 + m * 16 + 4 * lg;
#pragma unroll
        for (int nn = 0; nn < 4; ++nn) {
            const int cg = bn * 128 + wc * 64 + nn * 16 + lr;
#pragma unroll
            for (int r = 0; r < 4; ++r)
                C[(size_t)(rg + r) * N + cg] = (OutT)acc[m][nn][r];
        }
    }
}

// ---------------------------------------------------------------------------
// Causal flash attention v7: 512 blocks x 256 thr (4 waves x 16 q-rows,
// QBLK=64=KVBLK). Block handles q-tile pair {p, 63-p} -> 65 tile-units per
// block, 2 identical blocks/CU (balance independent of dispatch pairing;
// barriers of the two blocks interleave). All waves compute all staged
// tiles; masking only at t==qt. Key-permuted V (P in registers), ring-3,
// deferred reductions, defer-max.
// K LDS [64][64] with XOR-16B swizzle (col8 ^= row&7): phase-conflict-free
// on write and frag read. V^T [64][64] 8B-block swizzle (R6 layout).
// ---------------------------------------------------------------------------
__global__ __launch_bounds__(256) void attn_kernel(const __bf16* __restrict__ qkv,
                                                   __bf16* __restrict__ attn_out) {
    const int bid = blockIdx.x;                      // 512 blocks
    const int swz = (bid & 7) * 64 + (bid >> 3);     // XCD-major
    const int bh  = swz >> 5;                        // 2 heads per XCD
    const int p   = swz & 31;                        // pair id 0..31
    const int b = bh >> 3, h = bh & 7;
    const int tid = threadIdx.x;
    const int w = tid >> 6, l = tid & 63, lg = l >> 4, lr = l & 15;

    __shared__ __align__(16) __bf16 Ks[3][64 * 64];
    __shared__ __align__(16) __bf16 Vt[3][64 * 64];

    const size_t rs = 1536;
    const __bf16* qbase = qkv + (size_t)b * 4096 * rs + h * 64;
    const __bf16* kbase = qbase + 512;
    const __bf16* vbase = qbase + 1024;

    // K staging: rows krow, krow+32; col chunk kc; elem col' = kc ^ 8*(row&7)
    const int krow = tid >> 3, kc = (tid & 7) * 8;
    const int kcx = kc ^ ((krow & 7) << 3);
    // V staging: keys 8*va2..+7 (a-groups a0,a1), d-pair vd
    const int va2 = tid >> 5;
    const int vd  = (tid & 31) * 2;
    const int a0 = 2 * va2, a1 = a0 + 1;
    const int vc0 = 8 * (a0 >> 3) + 2 * (a0 & 3) + ((a0 >> 2) & 1);
    const int vc1 = 8 * (a1 >> 3) + 2 * (a1 & 3) + ((a1 >> 2) & 1);
    const int vm0 = (vd ^ (vd >> 2)) & 15;
    const int vm1 = ((vd + 1) ^ ((vd + 1) >> 2)) & 15;

    bf16x8 kreg0, kreg1;
    uint vreg[8];

    auto stage_load = [&](int kt2) {
        const int k0n = kt2 * 64;
        kreg0 = *reinterpret_cast<const bf16x8*>(kbase + (size_t)(k0n + krow) * rs + kc);
        kreg1 = *reinterpret_cast<const bf16x8*>(kbase + (size_t)(k0n + krow + 32) * rs + kc);
        const __bf16* vp = vbase + (size_t)(k0n + 8 * va2) * rs + vd;
#pragma unroll
        for (int q = 0; q < 8; ++q)
            vreg[q] = *reinterpret_cast<const uint*>(vp + (size_t)q * rs);
    };
    auto stage_write = [&](int nx) {
        *reinterpret_cast<bf16x8*>(&Ks[nx][krow * 64 + kcx])        = kreg0;
        *reinterpret_cast<bf16x8*>(&Ks[nx][(krow + 32) * 64 + kcx]) = kreg1;
        union { uint u; __bf16 h[2]; } sp;
        union { __bf16 h[4]; uint2 u; } wa0, wa1, wb0, wb1;
#pragma unroll
        for (int q = 0; q < 4; ++q) {
            sp.u = vreg[q];     wa0.h[q] = sp.h[0]; wb0.h[q] = sp.h[1];
            sp.u = vreg[q + 4]; wa1.h[q] = sp.h[0]; wb1.h[q] = sp.h[1];
        }
        *reinterpret_cast<uint2*>(&Vt[nx][vd * 64 + ((vc0 ^ vm0) << 2)])       = wa0.u;
        *reinterpret_cast<uint2*>(&Vt[nx][vd * 64 + ((vc1 ^ vm0) << 2)])       = wa1.u;
        *reinterpret_cast<uint2*>(&Vt[nx][(vd + 1) * 64 + ((vc0 ^ vm1) << 2)]) = wb0.u;
        *reinterpret_cast<uint2*>(&Vt[nx][(vd + 1) * 64 + ((vc1 ^ vm1) << 2)]) = wb1.u;
    };

    for (int seg = 0; seg < 2; ++seg) {
        const int qt = seg ? (63 - p) : p;
        const int wq0 = qt * 64 + 16 * w;

        bf16x8 Qf[2];
#pragma unroll
        for (int kh = 0; kh < 2; ++kh)
            Qf[kh] = *reinterpret_cast<const bf16x8*>(
                qbase + (size_t)(wq0 + lr) * rs + 32 * kh + 8 * lg);

        auto qk = [&](f32x4* S, int bufi) {
            __builtin_amdgcn_s_setprio(1);
#pragma unroll
            for (int jt = 0; jt < 4; ++jt) {
                const int row = 16 * jt + lr;
                const __bf16* kr = &Ks[bufi][row * 64];
                const int x = (lr & 7) << 3;
                const bf16x8 Kf0 = *reinterpret_cast<const bf16x8*>(kr + ((8 * lg) ^ x));
                const bf16x8 Kf1 = *reinterpret_cast<const bf16x8*>(kr + ((32 + 8 * lg) ^ x));
                S[jt] = __builtin_amdgcn_mfma_f32_16x16x32_bf16(Kf0, Qf[0], S[jt], 0, 0, 0);
                S[jt] = __builtin_amdgcn_mfma_f32_16x16x32_bf16(Kf1, Qf[1], S[jt], 0, 0, 0);
            }
            __builtin_amdgcn_s_setprio(0);
        };

        f32x4 O[4] = {};
        float m_ = -1e30f, l_ = 0.0f;
        const int nkt = qt + 1;

        stage_load(0);
        stage_write(0);
        stage_load(1);                       // tile 1 always valid memory
        stage_write(1);
        __syncthreads();
        f32x4 Sp[4] = {};
        qk(Sp, 0);

        for (int t = 0; t < nkt; ++t) {
            const int bcur = t % 3;
            const bool more2 = (t + 2 < nkt);
            if (more2) stage_load(t + 2);

            f32x4 Sn[4] = {};
            if (t + 1 < nkt) qk(Sn, (t + 1) % 3);

            if (t == nkt - 1) {              // diagonal tile: mask
#pragma unroll
                for (int jt = 0; jt < 4; ++jt)
#pragma unroll
                    for (int r = 0; r < 4; ++r)
                        if (16 * jt + 4 * lg + r > 16 * w + lr) Sp[jt][r] = -1e30f;
            }
            // lane-local max; cross-lane reduce only on (rare) rescale
            float mx = -1e30f;
#pragma unroll
            for (int jt = 0; jt < 4; ++jt)
                mx = fmaxf(mx, fmaxf(fmaxf(Sp[jt][0], Sp[jt][1]), fmaxf(Sp[jt][2], Sp[jt][3])));
            if (__any(mx > m_ + 8.0f)) {
                mx = fmaxf(mx, __shfl_xor(mx, 16));
                mx = fmaxf(mx, __shfl_xor(mx, 32));
                const float mn = fmaxf(m_, mx);
                const float alpha = __builtin_amdgcn_exp2f(m_ - mn);
                m_ = mn;
                l_ *= alpha;
#pragma unroll
                for (int dt = 0; dt < 4; ++dt) O[dt] *= alpha;
            }
            float sum = 0.0f;
#pragma unroll
            for (int jt = 0; jt < 4; ++jt)
#pragma unroll
                for (int r = 0; r < 4; ++r) {
                    const float pv = __builtin_amdgcn_exp2f(Sp[jt][r] - m_);
                    Sp[jt][r] = pv;
                    sum += pv;
                }
            l_ += sum;
            // P pack (lane-local via kappa-permuted V) + PV
            __builtin_amdgcn_s_setprio(1);
#pragma unroll
            for (int s = 0; s < 2; ++s) {
                bf16x8 Pf;
#pragma unroll
                for (int i = 0; i < 8; ++i)
                    Pf[i] = (__bf16)Sp[2 * s + (i >> 2)][i & 3];
#pragma unroll
                for (int dt = 0; dt < 4; ++dt) {
                    const int row = 16 * dt + lr;
                    const int m = (row ^ (row >> 2)) & 15;
                    const __bf16* vrow = &Vt[bcur][row * 64];
                    const int c0 = 8 * s + 2 * lg;
                    union { uint2 u2[2]; bf16x8 v; } vf;
                    vf.u2[0] = *reinterpret_cast<const uint2*>(vrow + ((c0 ^ m) << 2));
                    vf.u2[1] = *reinterpret_cast<const uint2*>(vrow + (((c0 + 1) ^ m) << 2));
                    O[dt] = __builtin_amdgcn_mfma_f32_16x16x32_bf16(vf.v, Pf, O[dt], 0, 0, 0);
                }
            }
            __builtin_amdgcn_s_setprio(0);

            if (more2) stage_write((t + 2) % 3);
            __syncthreads();
#pragma unroll
            for (int jt = 0; jt < 4; ++jt) Sp[jt] = Sn[jt];
        }

        // epilogue: deferred row-sum of l, then O / l
        float lt = l_;
        lt += __shfl_xor(lt, 16);
        lt += __shfl_xor(lt, 32);
        const float inv = 1.0f / lt;
        __bf16* op = attn_out + ((size_t)b * 4096 + wq0 + lr) * 512 + h * 64;
#pragma unroll
        for (int dt = 0; dt < 4; ++dt) {
            union { __bf16 h[4]; uint2 u; } ow;
#pragma unroll
            for (int r = 0; r < 4; ++r) ow.h[r] = (__bf16)(O[dt][r] * inv);
            *reinterpret_cast<uint2*>(op + 16 * dt + 4 * lg) = ow.u;
        }
    }
}

// ---------------------------------------------------------------------------
extern "C" void kernel_launch(void* const* d_in, const int* in_sizes, int n_in,
                              void* d_out, int out_size, void* d_ws, size_t ws_size,
                              hipStream_t stream) {
    (void)in_sizes; (void)n_in; (void)out_size; (void)ws_size;
    const float* x    = (const float*)d_in[0];
    const float* rot  = (const float*)d_in[1];
    const float* rmsw = (const float*)d_in[2];
    const float* wqkv = (const float*)d_in[3];
    const float* wout = (const float*)d_in[4];
    float* out = (float*)d_out;

    char* ws = (char*)d_ws;
    __bf16* xn    = (__bf16*)ws;                       // 16,777,216 B
    __bf16* wqkvt = (__bf16*)(ws + 16777216);          //  3,145,728 B
    __bf16* woutt = (__bf16*)(ws + 16777216 + 3145728);//  1,048,576 B
    __bf16* aout  = (__bf16*)(ws + 16777216 + 3145728 + 1048576); // 8,388,608 B
    // d_out layout during pipeline: qkv scratch [0, 25165824), csin table
    // [25165824, 27262976) — both dead by the time gemm_out writes d_out.
    __bf16* qkv   = (__bf16*)d_out;
    float2* csin  = (float2*)((char*)d_out + 25165824);

    rmsnorm_kernel<<<8192, 256, 0, stream>>>(x, rmsw, xn);
    transpose_cast_kernel<<<dim3(48, 32), dim3(32, 8), 0, stream>>>(wqkv, wqkvt, 1024, 1536);
    transpose_cast_kernel<<<dim3(32, 16), dim3(32, 8), 0, stream>>>(wout, woutt, 512, 1024);
    csin_kernel<<<1024, 256, 0, stream>>>(rot, csin);
    gemm_bt<__bf16, true><<<dim3(12, 64), 256, 0, stream>>>(xn, wqkvt, qkv, 8192, 1536, 1024, csin);
    attn_kernel<<<512, 256, 0, stream>>>(qkv, aout);
    gemm_bt<float, false><<<dim3(8, 64), 256, 0, stream>>>(aout, woutt, out, 8192, 1024, 512, nullptr);
}

// Round 8
// 156.017 us; speedup vs baseline: 1.1307x; 1.1307x over previous
//
#include <hip/hip_runtime.h>
#include <hip/hip_bf16.h>
#include <cstdint>

using bf16x8 = __attribute__((ext_vector_type(8))) __bf16;
using f32x4  = __attribute__((ext_vector_type(4))) float;

#define LOG2E 1.4426950408889634f

__device__ inline void gload16(__bf16* lds, const __bf16* g) {
    __builtin_amdgcn_global_load_lds((const __attribute__((address_space(1))) void*)g,
                                     (__attribute__((address_space(3))) void*)lds, 16, 0, 0);
}

// ---------------------------------------------------------------------------
// RMSNorm: one block (256 threads) per row of 1024 fp32 -> bf16
// ---------------------------------------------------------------------------
__global__ __launch_bounds__(256) void rmsnorm_kernel(const float* __restrict__ x,
                                                      const float* __restrict__ w,
                                                      __bf16* __restrict__ xn) {
    const int row = blockIdx.x;
    const float4 v = reinterpret_cast<const float4*>(x + (size_t)row * 1024)[threadIdx.x];
    float ss = v.x * v.x + v.y * v.y + v.z * v.z + v.w * v.w;
#pragma unroll
    for (int i = 1; i < 64; i <<= 1) ss += __shfl_xor(ss, i);
    __shared__ float part[4];
    if ((threadIdx.x & 63) == 0) part[threadIdx.x >> 6] = ss;
    __syncthreads();
    const float total = part[0] + part[1] + part[2] + part[3];
    const float scale = rsqrtf(total * (1.0f / 1024.0f) + 1.1920929e-07f);
    const float4 wv = reinterpret_cast<const float4*>(w)[threadIdx.x];
    union { __bf16 h[4]; uint2 u; } pk;
    pk.h[0] = (__bf16)(v.x * scale * wv.x);
    pk.h[1] = (__bf16)(v.y * scale * wv.y);
    pk.h[2] = (__bf16)(v.z * scale * wv.z);
    pk.h[3] = (__bf16)(v.w * scale * wv.w);
    reinterpret_cast<uint2*>(xn + (size_t)row * 1024)[threadIdx.x] = pk.u;
}

// ---------------------------------------------------------------------------
// Transpose + cast: in (K x N) fp32 row-major -> out (N x K) bf16 row-major
// ---------------------------------------------------------------------------
__global__ void transpose_cast_kernel(const float* __restrict__ in,
                                      __bf16* __restrict__ out, int K, int N) {
    __shared__ float tile[32][33];
    const int n0 = blockIdx.x * 32, k0 = blockIdx.y * 32;
#pragma unroll
    for (int r = threadIdx.y; r < 32; r += 8)
        tile[r][threadIdx.x] = in[(size_t)(k0 + r) * N + n0 + threadIdx.x];
    __syncthreads();
#pragma unroll
    for (int r = threadIdx.y; r < 32; r += 8)
        out[(size_t)(n0 + r) * K + k0 + threadIdx.x] = (__bf16)tile[threadIdx.x][r];
}

// ---------------------------------------------------------------------------
// cos/sin table: csin[pos*64+d] = (cos, sin) of rot[pos][d]. 262144 entries.
// ---------------------------------------------------------------------------
__global__ __launch_bounds__(256) void csin_kernel(const float* __restrict__ rot,
                                                   float2* __restrict__ csin) {
    const int i = blockIdx.x * 256 + threadIdx.x;
    float s, c;
    sincosf(rot[i], &s, &c);
    csin[i] = make_float2(c, s);
}

// ---------------------------------------------------------------------------
// RoPE (table-based) in-place on qk [8192][1024]; q (cols<512) also scaled by
// d^-0.5 * log2(e). One wave per (b,pos): lane = h*8 + d-quad.
// ---------------------------------------------------------------------------
__global__ __launch_bounds__(256) void rope_kernel(__bf16* __restrict__ qk,
                                                   const float2* __restrict__ csin) {
    const int row = blockIdx.x * 4 + (threadIdx.x >> 6);   // b*4096+pos
    const int lane = threadIdx.x & 63;
    const int h = lane >> 3, dl = (lane & 7) * 4;
    const int pos = row & 4095;
    const float4 csA = *reinterpret_cast<const float4*>(&csin[pos * 64 + dl]);
    const float4 csB = *reinterpret_cast<const float4*>(&csin[pos * 64 + dl + 2]);
    const float4 csC = *reinterpret_cast<const float4*>(&csin[pos * 64 + dl + 32]);
    const float4 csD = *reinterpret_cast<const float4*>(&csin[pos * 64 + dl + 34]);
    const float c0[4] = {csA.x, csA.z, csB.x, csB.z};
    const float s0[4] = {csA.y, csA.w, csB.y, csB.w};
    const float c1[4] = {csC.x, csC.z, csD.x, csD.z};
    const float s1[4] = {csC.y, csC.w, csD.y, csD.w};
    __bf16* p = qk + (size_t)row * 1024 + h * 64 + dl;
    const float qs = 0.125f * LOG2E;
#pragma unroll
    for (int part = 0; part < 2; ++part) {      // q then k
        __bf16* pp = p + part * 512;
        const float sc = part ? 1.0f : qs;
        union { uint2 u; __bf16 hh[4]; } va, vb, oa, ob;
        va.u = *reinterpret_cast<const uint2*>(pp);
        vb.u = *reinterpret_cast<const uint2*>(pp + 32);
#pragma unroll
        for (int j = 0; j < 4; ++j) {
            const float a = (float)va.hh[j], b2 = (float)vb.hh[j];
            oa.hh[j] = (__bf16)((a * c0[j] - b2 * s0[j]) * sc);
            ob.hh[j] = (__bf16)((b2 * c1[j] + a * s1[j]) * sc);
        }
        *reinterpret_cast<uint2*>(pp)      = oa.u;
        *reinterpret_cast<uint2*>(pp + 32) = ob.u;
    }
}

// ---------------------------------------------------------------------------
// GEMM: C(MxN) = A(MxK) @ Bt(NxK)^T, bf16 in, fp32 accum, gload16 staging.
// MODE 0: plain OutT output, ld = N.
// MODE 1 (QKV): cols <1024 -> qk buf [8192][1024] bf16; cols >=1024 (v) ->
//   vt[1024][4096] bf16, transposed + kappa-permuted within each 64-key tile
//   (kinv(a) = 32(a>>5) + 8((a>>2)&3) + 4((a>>4)&1) + (a&3)) so attention's
//   P-fragment is a pure lane-local register pack.
// ---------------------------------------------------------------------------
template <typename OutT, int MODE>
__global__ __launch_bounds__(256) void gemm_bt(const __bf16* __restrict__ A,
                                               const __bf16* __restrict__ Bt,
                                               OutT* __restrict__ C,
                                               __bf16* __restrict__ vt,
                                               int M, int N, int K) {
    __shared__ __align__(16) __bf16 As[128 * 32];
    __shared__ __align__(16) __bf16 Bs[128 * 32];
    const int bm = blockIdx.y, bn = blockIdx.x;
    const int tid = threadIdx.x;
    const int w = tid >> 6, l = tid & 63, lg = l >> 4, lr = l & 15;
    const int wr = w >> 1, wc = w & 1;
    const __bf16* Ab = A + (size_t)(bm * 128) * K;
    const __bf16* Bb = Bt + (size_t)(bn * 128) * K;
    const int srow = tid >> 2, scol = (tid & 3) * 8;
    f32x4 acc[4][4] = {};
    for (int k0 = 0; k0 < K; k0 += 32) {
        gload16(As + tid * 8,        Ab + (size_t)srow * K + k0 + scol);
        gload16(As + 2048 + tid * 8, Ab + (size_t)(srow + 64) * K + k0 + scol);
        gload16(Bs + tid * 8,        Bb + (size_t)srow * K + k0 + scol);
        gload16(Bs + 2048 + tid * 8, Bb + (size_t)(srow + 64) * K + k0 + scol);
        __syncthreads();
        bf16x8 af[4], bfr[4];
#pragma unroll
        for (int m = 0; m < 4; ++m)
            af[m] = *reinterpret_cast<const bf16x8*>(&As[(wr * 64 + m * 16 + lr) * 32 + lg * 8]);
#pragma unroll
        for (int nn = 0; nn < 4; ++nn)
            bfr[nn] = *reinterpret_cast<const bf16x8*>(&Bs[(wc * 64 + nn * 16 + lr) * 32 + lg * 8]);
#pragma unroll
        for (int m = 0; m < 4; ++m)
#pragma unroll
            for (int nn = 0; nn < 4; ++nn)
                acc[m][nn] = __builtin_amdgcn_mfma_f32_16x16x32_bf16(af[m], bfr[nn],
                                                                     acc[m][nn], 0, 0, 0);
        __syncthreads();
    }
    if constexpr (MODE == 1) {
        const int cb = bn * 128 + wc * 64;
        if (cb < 1024) {                          // q,k -> qk buf (ld 1024)
#pragma unroll
            for (int m = 0; m < 4; ++m) {
                const int rg = bm * 128 + wr * 64 + m * 16 + 4 * lg;
#pragma unroll
                for (int nn = 0; nn < 4; ++nn) {
                    const int cg = cb + nn * 16 + lr;
#pragma unroll
                    for (int r = 0; r < 4; ++r)
                        C[(size_t)(rg + r) * 1024 + cg] = (OutT)acc[m][nn][r];
                }
            }
        } else {                                  // v -> vt transposed + kappa
#pragma unroll
            for (int m = 0; m < 4; ++m) {
                const int rg = bm * 128 + wr * 64 + m * 16 + 4 * lg;
                const int bidx = rg >> 12, pos0 = rg & 4095;
                const int a0 = pos0 & 63;
                const int cp = 32 * (a0 >> 5) + 8 * ((a0 >> 2) & 3) + 4 * ((a0 >> 4) & 1);
                const int nbase = (pos0 & ~63) + cp;
#pragma unroll
                for (int nn = 0; nn < 4; ++nn) {
                    const int col = cb + nn * 16 + lr - 1024;
                    const int hh = col >> 6, dd = col & 63;
                    union { __bf16 h4[4]; uint2 u; } pk2;
#pragma unroll
                    for (int r = 0; r < 4; ++r) pk2.h4[r] = (__bf16)acc[m][nn][r];
                    *reinterpret_cast<uint2*>(&vt[((size_t)(bidx * 8 + hh) * 64 + dd) * 4096 + nbase]) = pk2.u;
                }
            }
        }
        return;
    }
#pragma unroll
    for (int m = 0; m < 4; ++m) {
        const int rg = bm * 128 + wr * 64 + m * 16 + 4 * lg;
#pragma unroll
        for (int nn = 0; nn < 4; ++nn) {
            const int cg = bn * 128 + wc * 64 + nn * 16 + lr;
#pragma unroll
            for (int r = 0; r < 4; ++r)
                C[(size_t)(rg + r) * N + cg] = (OutT)acc[m][nn][r];
        }
    }
}

// ---------------------------------------------------------------------------
// Causal flash attention v8: zero-VALU staging via global_load_lds for BOTH
// K (from qk buf) and V^T (from vt buf, pre-transposed + kappa-permuted by
// the QKV GEMM). Swizzle col8 ^= row&7 baked into per-lane GLOBAL source
// addresses, LDS linear (rule #21). 512 blocks x 256 thr (4 waves x 16
// q-rows), q-tile pair {p, 63-p} per block (balanced), ring-3 buffers,
// 1 barrier/tile, P in registers, deferred reductions, defer-max.
// ---------------------------------------------------------------------------
__global__ __launch_bounds__(256) void attn_kernel(const __bf16* __restrict__ qkp,
                                                   const __bf16* __restrict__ vt,
                                                   __bf16* __restrict__ attn_out) {
    const int bid = blockIdx.x;                      // 512 blocks
    const int swz = (bid & 7) * 64 + (bid >> 3);     // XCD-major
    const int bh  = swz >> 5;                        // 2 heads per XCD
    const int p   = swz & 31;                        // pair id 0..31
    const int b = bh >> 3, h = bh & 7;
    const int tid = threadIdx.x;
    const int w = tid >> 6, l = tid & 63, lg = l >> 4, lr = l & 15;

    __shared__ __align__(16) __bf16 Ks[3][64 * 64];
    __shared__ __align__(16) __bf16 Vs[3][64 * 64];

    const __bf16* qbase = qkp + (size_t)b * 4096 * 1024 + h * 64;
    const __bf16* kbase = qbase + 512;
    const __bf16* vtb   = vt + (size_t)(b * 8 + h) * 64 * 4096;

    // staging: chunk tid -> (row = tid>>3, col8 = tid&7); source col8 swizzled
    const int sr = tid >> 3;
    const int sc = ((tid & 7) ^ (sr & 7)) * 8;
    const __bf16* ksrc = kbase + (size_t)sr * 1024 + sc;
    const __bf16* vsrc = vtb + (size_t)sr * 4096 + sc;

    auto stage_issue = [&](int kt2) {
        const int nx = kt2 % 3;
        const int off = kt2 * 64;
        gload16(&Ks[nx][tid * 8],         ksrc + (size_t)off * 1024);
        gload16(&Ks[nx][(tid + 256) * 8], ksrc + (size_t)(off + 32) * 1024);
        gload16(&Vs[nx][tid * 8],         vsrc + off);
        gload16(&Vs[nx][(tid + 256) * 8], vsrc + 32 * 4096 + off);
    };

    const int xel = (lr & 7) * 8;                    // read-side swizzle

    for (int seg = 0; seg < 2; ++seg) {
        const int qt = seg ? (63 - p) : p;
        const int wq0 = qt * 64 + 16 * w;

        bf16x8 Qf[2];
#pragma unroll
        for (int kh = 0; kh < 2; ++kh)
            Qf[kh] = *reinterpret_cast<const bf16x8*>(
                qbase + (size_t)(wq0 + lr) * 1024 + 32 * kh + 8 * lg);

        auto qk = [&](f32x4* S, int bufi) {
            __builtin_amdgcn_s_setprio(1);
#pragma unroll
            for (int jt = 0; jt < 4; ++jt) {
                const __bf16* kr = &Ks[bufi][(16 * jt + lr) * 64];
                const bf16x8 Kf0 = *reinterpret_cast<const bf16x8*>(kr + ((8 * lg) ^ xel));
                const bf16x8 Kf1 = *reinterpret_cast<const bf16x8*>(kr + ((32 + 8 * lg) ^ xel));
                S[jt] = __builtin_amdgcn_mfma_f32_16x16x32_bf16(Kf0, Qf[0], S[jt], 0, 0, 0);
                S[jt] = __builtin_amdgcn_mfma_f32_16x16x32_bf16(Kf1, Qf[1], S[jt], 0, 0, 0);
            }
            __builtin_amdgcn_s_setprio(0);
        };

        f32x4 O[4] = {};
        float m_ = -1e30f, l_ = 0.0f;
        const int nkt = qt + 1;

        stage_issue(0);
        stage_issue(1);                  // always valid memory
        __syncthreads();
        f32x4 Sp[4] = {};
        qk(Sp, 0);

        for (int t = 0; t < nkt; ++t) {
            const int bcur = t % 3;
            if (t + 2 < nkt) stage_issue(t + 2);

            f32x4 Sn[4] = {};
            if (t + 1 < nkt) qk(Sn, (t + 1) % 3);

            if (t == nkt - 1) {              // diagonal tile: mask
#pragma unroll
                for (int jt = 0; jt < 4; ++jt)
#pragma unroll
                    for (int r = 0; r < 4; ++r)
                        if (16 * jt + 4 * lg + r > 16 * w + lr) Sp[jt][r] = -1e30f;
            }
            float mx = -1e30f;
#pragma unroll
            for (int jt = 0; jt < 4; ++jt)
                mx = fmaxf(mx, fmaxf(fmaxf(Sp[jt][0], Sp[jt][1]), fmaxf(Sp[jt][2], Sp[jt][3])));
            if (__any(mx > m_ + 8.0f)) {
                mx = fmaxf(mx, __shfl_xor(mx, 16));
                mx = fmaxf(mx, __shfl_xor(mx, 32));
                const float mn = fmaxf(m_, mx);
                const float alpha = __builtin_amdgcn_exp2f(m_ - mn);
                m_ = mn;
                l_ *= alpha;
#pragma unroll
                for (int dt = 0; dt < 4; ++dt) O[dt] *= alpha;
            }
            float sum = 0.0f;
#pragma unroll
            for (int jt = 0; jt < 4; ++jt)
#pragma unroll
                for (int r = 0; r < 4; ++r) {
                    const float pv = __builtin_amdgcn_exp2f(Sp[jt][r] - m_);
                    Sp[jt][r] = pv;
                    sum += pv;
                }
            l_ += sum;
            // P pack (lane-local, kappa baked into vt) + PV
            __builtin_amdgcn_s_setprio(1);
#pragma unroll
            for (int s = 0; s < 2; ++s) {
                bf16x8 Pf;
#pragma unroll
                for (int i = 0; i < 8; ++i)
                    Pf[i] = (__bf16)Sp[2 * s + (i >> 2)][i & 3];
#pragma unroll
                for (int dt = 0; dt < 4; ++dt) {
                    const bf16x8 Vf = *reinterpret_cast<const bf16x8*>(
                        &Vs[bcur][(16 * dt + lr) * 64 + ((32 * s + 8 * lg) ^ xel)]);
                    O[dt] = __builtin_amdgcn_mfma_f32_16x16x32_bf16(Vf, Pf, O[dt], 0, 0, 0);
                }
            }
            __builtin_amdgcn_s_setprio(0);

            __syncthreads();
#pragma unroll
            for (int jt = 0; jt < 4; ++jt) Sp[jt] = Sn[jt];
        }

        float lt = l_;
        lt += __shfl_xor(lt, 16);
        lt += __shfl_xor(lt, 32);
        const float inv = 1.0f / lt;
        __bf16* op = attn_out + ((size_t)b * 4096 + wq0 + lr) * 512 + h * 64;
#pragma unroll
        for (int dt = 0; dt < 4; ++dt) {
            union { __bf16 h4[4]; uint2 u; } ow;
#pragma unroll
            for (int r = 0; r < 4; ++r) ow.h4[r] = (__bf16)(O[dt][r] * inv);
            *reinterpret_cast<uint2*>(op + 16 * dt + 4 * lg) = ow.u;
        }
    }
}

// ---------------------------------------------------------------------------
extern "C" void kernel_launch(void* const* d_in, const int* in_sizes, int n_in,
                              void* d_out, int out_size, void* d_ws, size_t ws_size,
                              hipStream_t stream) {
    (void)in_sizes; (void)n_in; (void)out_size; (void)ws_size;
    const float* x    = (const float*)d_in[0];
    const float* rot  = (const float*)d_in[1];
    const float* rmsw = (const float*)d_in[2];
    const float* wqkv = (const float*)d_in[3];
    const float* wout = (const float*)d_in[4];
    float* out = (float*)d_out;

    char* ws = (char*)d_ws;
    __bf16* xn    = (__bf16*)ws;                       // 16,777,216 B
    __bf16* wqkvt = (__bf16*)(ws + 16777216);          //  3,145,728 B
    __bf16* woutt = (__bf16*)(ws + 16777216 + 3145728);//  1,048,576 B
    __bf16* aout  = (__bf16*)(ws + 16777216 + 3145728 + 1048576); // 8,388,608 B
    // d_out during pipeline: qk [0,16.78M), csin [16.78M,18.87M),
    // vt [18.87M,27.26M) — all dead before the final GEMM overwrites d_out.
    __bf16* qk   = (__bf16*)d_out;
    float2* csin = (float2*)((char*)d_out + 16777216);
    __bf16* vt   = (__bf16*)((char*)d_out + 18874368);

    rmsnorm_kernel<<<8192, 256, 0, stream>>>(x, rmsw, xn);
    transpose_cast_kernel<<<dim3(48, 32), dim3(32, 8), 0, stream>>>(wqkv, wqkvt, 1024, 1536);
    transpose_cast_kernel<<<dim3(32, 16), dim3(32, 8), 0, stream>>>(wout, woutt, 512, 1024);
    csin_kernel<<<1024, 256, 0, stream>>>(rot, csin);
    gemm_bt<__bf16, 1><<<dim3(12, 64), 256, 0, stream>>>(xn, wqkvt, qk, vt, 8192, 1536, 1024);
    rope_kernel<<<2048, 256, 0, stream>>>(qk, csin);
    attn_kernel<<<512, 256, 0, stream>>>(qk, vt, aout);
    gemm_bt<float, 0><<<dim3(8, 64), 256, 0, stream>>>(aout, woutt, out, nullptr, 8192, 1024, 512);
}

// Round 9
// 147.129 us; speedup vs baseline: 1.1990x; 1.0604x over previous
//
#include <hip/hip_runtime.h>
#include <hip/hip_bf16.h>
#include <cstdint>

using bf16x8 = __attribute__((ext_vector_type(8))) __bf16;
using f32x4  = __attribute__((ext_vector_type(4))) float;

#define LOG2E 1.4426950408889634f

__device__ inline void gload16(__bf16* lds, const __bf16* g) {
    __builtin_amdgcn_global_load_lds((const __attribute__((address_space(1))) void*)g,
                                     (__attribute__((address_space(3))) void*)lds, 16, 0, 0);
}

// ---------------------------------------------------------------------------
// RMSNorm: one block (256 threads) per row of 1024 fp32 -> bf16
// ---------------------------------------------------------------------------
__global__ __launch_bounds__(256) void rmsnorm_kernel(const float* __restrict__ x,
                                                      const float* __restrict__ w,
                                                      __bf16* __restrict__ xn) {
    const int row = blockIdx.x;
    const float4 v = reinterpret_cast<const float4*>(x + (size_t)row * 1024)[threadIdx.x];
    float ss = v.x * v.x + v.y * v.y + v.z * v.z + v.w * v.w;
#pragma unroll
    for (int i = 1; i < 64; i <<= 1) ss += __shfl_xor(ss, i);
    __shared__ float part[4];
    if ((threadIdx.x & 63) == 0) part[threadIdx.x >> 6] = ss;
    __syncthreads();
    const float total = part[0] + part[1] + part[2] + part[3];
    const float scale = rsqrtf(total * (1.0f / 1024.0f) + 1.1920929e-07f);
    const float4 wv = reinterpret_cast<const float4*>(w)[threadIdx.x];
    union { __bf16 h[4]; uint2 u; } pk;
    pk.h[0] = (__bf16)(v.x * scale * wv.x);
    pk.h[1] = (__bf16)(v.y * scale * wv.y);
    pk.h[2] = (__bf16)(v.z * scale * wv.z);
    pk.h[3] = (__bf16)(v.w * scale * wv.w);
    reinterpret_cast<uint2*>(xn + (size_t)row * 1024)[threadIdx.x] = pk.u;
}

// ---------------------------------------------------------------------------
// Transpose + cast: in (K x N) fp32 row-major -> out (N x K) bf16 row-major
// ---------------------------------------------------------------------------
__global__ void transpose_cast_kernel(const float* __restrict__ in,
                                      __bf16* __restrict__ out, int K, int N) {
    __shared__ float tile[32][33];
    const int n0 = blockIdx.x * 32, k0 = blockIdx.y * 32;
#pragma unroll
    for (int r = threadIdx.y; r < 32; r += 8)
        tile[r][threadIdx.x] = in[(size_t)(k0 + r) * N + n0 + threadIdx.x];
    __syncthreads();
#pragma unroll
    for (int r = threadIdx.y; r < 32; r += 8)
        out[(size_t)(n0 + r) * K + k0 + threadIdx.x] = (__bf16)tile[threadIdx.x][r];
}

// ---------------------------------------------------------------------------
// cos/sin table: csin[pos*64+d] = (cos, sin) of rot[pos][d]. 262144 entries.
// ---------------------------------------------------------------------------
__global__ __launch_bounds__(256) void csin_kernel(const float* __restrict__ rot,
                                                   float2* __restrict__ csin) {
    const int i = blockIdx.x * 256 + threadIdx.x;
    float s, c;
    sincosf(rot[i], &s, &c);
    csin[i] = make_float2(c, s);
}

// ---------------------------------------------------------------------------
// RoPE (table-based) in-place on qk [8192][1024]; q (cols<512) also scaled by
// d^-0.5 * log2(e). One wave per (b,pos): lane = h*8 + d-quad.
// ---------------------------------------------------------------------------
__global__ __launch_bounds__(256) void rope_kernel(__bf16* __restrict__ qk,
                                                   const float2* __restrict__ csin) {
    const int row = blockIdx.x * 4 + (threadIdx.x >> 6);   // b*4096+pos
    const int lane = threadIdx.x & 63;
    const int h = lane >> 3, dl = (lane & 7) * 4;
    const int pos = row & 4095;
    const float4 csA = *reinterpret_cast<const float4*>(&csin[pos * 64 + dl]);
    const float4 csB = *reinterpret_cast<const float4*>(&csin[pos * 64 + dl + 2]);
    const float4 csC = *reinterpret_cast<const float4*>(&csin[pos * 64 + dl + 32]);
    const float4 csD = *reinterpret_cast<const float4*>(&csin[pos * 64 + dl + 34]);
    const float c0[4] = {csA.x, csA.z, csB.x, csB.z};
    const float s0[4] = {csA.y, csA.w, csB.y, csB.w};
    const float c1[4] = {csC.x, csC.z, csD.x, csD.z};
    const float s1[4] = {csC.y, csC.w, csD.y, csD.w};
    __bf16* p = qk + (size_t)row * 1024 + h * 64 + dl;
    const float qs = 0.125f * LOG2E;
#pragma unroll
    for (int part = 0; part < 2; ++part) {      // q then k
        __bf16* pp = p + part * 512;
        const float sc = part ? 1.0f : qs;
        union { uint2 u; __bf16 hh[4]; } va, vb, oa, ob;
        va.u = *reinterpret_cast<const uint2*>(pp);
        vb.u = *reinterpret_cast<const uint2*>(pp + 32);
#pragma unroll
        for (int j = 0; j < 4; ++j) {
            const float a = (float)va.hh[j], b2 = (float)vb.hh[j];
            oa.hh[j] = (__bf16)((a * c0[j] - b2 * s0[j]) * sc);
            ob.hh[j] = (__bf16)((b2 * c1[j] + a * s1[j]) * sc);
        }
        *reinterpret_cast<uint2*>(pp)      = oa.u;
        *reinterpret_cast<uint2*>(pp + 32) = ob.u;
    }
}

// ---------------------------------------------------------------------------
// GEMM: C(MxN) = A(MxK) @ Bt(NxK)^T, bf16 in, fp32 accum, gload16 staging.
// MODE 0: plain OutT output, ld = N.
// MODE 1 (QKV): cols <1024 -> qk buf [8192][1024] bf16; cols >=1024 (v) ->
//   vt[1024][4096] bf16, transposed + kappa-permuted within each 64-key tile.
// ---------------------------------------------------------------------------
template <typename OutT, int MODE>
__global__ __launch_bounds__(256) void gemm_bt(const __bf16* __restrict__ A,
                                               const __bf16* __restrict__ Bt,
                                               OutT* __restrict__ C,
                                               __bf16* __restrict__ vt,
                                               int M, int N, int K) {
    __shared__ __align__(16) __bf16 As[128 * 32];
    __shared__ __align__(16) __bf16 Bs[128 * 32];
    const int bm = blockIdx.y, bn = blockIdx.x;
    const int tid = threadIdx.x;
    const int w = tid >> 6, l = tid & 63, lg = l >> 4, lr = l & 15;
    const int wr = w >> 1, wc = w & 1;
    const __bf16* Ab = A + (size_t)(bm * 128) * K;
    const __bf16* Bb = Bt + (size_t)(bn * 128) * K;
    const int srow = tid >> 2, scol = (tid & 3) * 8;
    f32x4 acc[4][4] = {};
    for (int k0 = 0; k0 < K; k0 += 32) {
        gload16(As + tid * 8,        Ab + (size_t)srow * K + k0 + scol);
        gload16(As + 2048 + tid * 8, Ab + (size_t)(srow + 64) * K + k0 + scol);
        gload16(Bs + tid * 8,        Bb + (size_t)srow * K + k0 + scol);
        gload16(Bs + 2048 + tid * 8, Bb + (size_t)(srow + 64) * K + k0 + scol);
        __syncthreads();
        bf16x8 af[4], bfr[4];
#pragma unroll
        for (int m = 0; m < 4; ++m)
            af[m] = *reinterpret_cast<const bf16x8*>(&As[(wr * 64 + m * 16 + lr) * 32 + lg * 8]);
#pragma unroll
        for (int nn = 0; nn < 4; ++nn)
            bfr[nn] = *reinterpret_cast<const bf16x8*>(&Bs[(wc * 64 + nn * 16 + lr) * 32 + lg * 8]);
#pragma unroll
        for (int m = 0; m < 4; ++m)
#pragma unroll
            for (int nn = 0; nn < 4; ++nn)
                acc[m][nn] = __builtin_amdgcn_mfma_f32_16x16x32_bf16(af[m], bfr[nn],
                                                                     acc[m][nn], 0, 0, 0);
        __syncthreads();
    }
    if constexpr (MODE == 1) {
        const int cb = bn * 128 + wc * 64;
        if (cb < 1024) {                          // q,k -> qk buf (ld 1024)
#pragma unroll
            for (int m = 0; m < 4; ++m) {
                const int rg = bm * 128 + wr * 64 + m * 16 + 4 * lg;
#pragma unroll
                for (int nn = 0; nn < 4; ++nn) {
                    const int cg = cb + nn * 16 + lr;
#pragma unroll
                    for (int r = 0; r < 4; ++r)
                        C[(size_t)(rg + r) * 1024 + cg] = (OutT)acc[m][nn][r];
                }
            }
        } else {                                  // v -> vt transposed + kappa
#pragma unroll
            for (int m = 0; m < 4; ++m) {
                const int rg = bm * 128 + wr * 64 + m * 16 + 4 * lg;
                const int bidx = rg >> 12, pos0 = rg & 4095;
                const int a0 = pos0 & 63;
                const int cp = 32 * (a0 >> 5) + 8 * ((a0 >> 2) & 3) + 4 * ((a0 >> 4) & 1);
                const int nbase = (pos0 & ~63) + cp;
#pragma unroll
                for (int nn = 0; nn < 4; ++nn) {
                    const int col = cb + nn * 16 + lr - 1024;
                    const int hh = col >> 6, dd = col & 63;
                    union { __bf16 h4[4]; uint2 u; } pk2;
#pragma unroll
                    for (int r = 0; r < 4; ++r) pk2.h4[r] = (__bf16)acc[m][nn][r];
                    *reinterpret_cast<uint2*>(&vt[((size_t)(bidx * 8 + hh) * 64 + dd) * 4096 + nbase]) = pk2.u;
                }
            }
        }
        return;
    }
#pragma unroll
    for (int m = 0; m < 4; ++m) {
        const int rg = bm * 128 + wr * 64 + m * 16 + 4 * lg;
#pragma unroll
        for (int nn = 0; nn < 4; ++nn) {
            const int cg = bn * 128 + wc * 64 + nn * 16 + lr;
#pragma unroll
            for (int r = 0; r < 4; ++r)
                C[(size_t)(rg + r) * N + cg] = (OutT)acc[m][nn][r];
        }
    }
}

// ---------------------------------------------------------------------------
// Causal flash attention v9: R8 structure with the tile loop UNROLLED x6
// (lcm of ring-3 buffers and 2-phase S alternation) so all LDS buffer
// indices and S-register roles are compile-time static (rule #20), staging
// uses two running global pointers (+const per tile), and main-loop bodies
// carry no mask/bounds checks (provably pre-diagonal). Dynamic tail <=7.
// Zero-VALU staging (global_load_lds, pre-swizzled source), P in registers,
// deferred reductions, defer-max. 512 blocks x 256 thr, pair {p, 63-p}.
// ---------------------------------------------------------------------------
__global__ __launch_bounds__(256) void attn_kernel(const __bf16* __restrict__ qkp,
                                                   const __bf16* __restrict__ vt,
                                                   __bf16* __restrict__ attn_out) {
    const int bid = blockIdx.x;                      // 512 blocks
    const int swz = (bid & 7) * 64 + (bid >> 3);     // XCD-major
    const int bh  = swz >> 5;                        // 2 heads per XCD
    const int p   = swz & 31;                        // pair id 0..31
    const int b = bh >> 3, h = bh & 7;
    const int tid = threadIdx.x;
    const int w = tid >> 6, l = tid & 63, lg = l >> 4, lr = l & 15;

    __shared__ __align__(16) __bf16 Ks[3][64 * 64];
    __shared__ __align__(16) __bf16 Vs[3][64 * 64];

    const __bf16* qbase = qkp + (size_t)b * 4096 * 1024 + h * 64;
    const __bf16* kbase = qbase + 512;
    const __bf16* vtb   = vt + (size_t)(b * 8 + h) * 64 * 4096;

    // staging: chunk tid -> (row = tid>>3, col8 = tid&7); source col8 swizzled
    const int sr = tid >> 3;
    const int sc = ((tid & 7) ^ (sr & 7)) * 8;
    const __bf16* ksrc0 = kbase + (size_t)sr * 1024 + sc;
    const __bf16* vsrc0 = vtb + (size_t)sr * 4096 + sc;

    const int xel = (lr & 7) * 8;                    // read-side swizzle

    for (int seg = 0; seg < 2; ++seg) {
        const int qt = seg ? (63 - p) : p;
        const int wq0 = qt * 64 + 16 * w;
        const int nkt = qt + 1;

        bf16x8 Qf[2];
#pragma unroll
        for (int kh = 0; kh < 2; ++kh)
            Qf[kh] = *reinterpret_cast<const bf16x8*>(
                qbase + (size_t)(wq0 + lr) * 1024 + 32 * kh + 8 * lg);

        f32x4 O[4] = {};
        float m_ = -1e30f, l_ = 0.0f;
        const __bf16* kp = ksrc0;        // advances 64*1024 per staged tile
        const __bf16* vp = vsrc0;        // advances 64 per staged tile

        auto stage2 = [&](__bf16* kdst, __bf16* vdst) {
            gload16(kdst + tid * 8,         kp);
            gload16(kdst + (tid + 256) * 8, kp + 32 * 1024);
            gload16(vdst + tid * 8,         vp);
            gload16(vdst + (tid + 256) * 8, vp + 32 * 4096);
            kp += 64 * 1024;
            vp += 64;
        };
        auto qk_step = [&](f32x4 (&S)[4], const __bf16* kb) {
            __builtin_amdgcn_s_setprio(1);
#pragma unroll
            for (int jt = 0; jt < 4; ++jt) {
                const __bf16* kr = kb + (16 * jt + lr) * 64;
                const bf16x8 Kf0 = *reinterpret_cast<const bf16x8*>(kr + ((8 * lg) ^ xel));
                const bf16x8 Kf1 = *reinterpret_cast<const bf16x8*>(kr + ((32 + 8 * lg) ^ xel));
                f32x4 z = {};
                z = __builtin_amdgcn_mfma_f32_16x16x32_bf16(Kf0, Qf[0], z, 0, 0, 0);
                S[jt] = __builtin_amdgcn_mfma_f32_16x16x32_bf16(Kf1, Qf[1], z, 0, 0, 0);
            }
            __builtin_amdgcn_s_setprio(0);
        };
        auto smpv = [&](f32x4 (&SC)[4], const __bf16* vb, bool domask) {
            if (domask) {
#pragma unroll
                for (int jt = 0; jt < 4; ++jt)
#pragma unroll
                    for (int r = 0; r < 4; ++r)
                        if (16 * jt + 4 * lg + r > 16 * w + lr) SC[jt][r] = -1e30f;
            }
            float mx = -1e30f;
#pragma unroll
            for (int jt = 0; jt < 4; ++jt)
                mx = fmaxf(mx, fmaxf(fmaxf(SC[jt][0], SC[jt][1]), fmaxf(SC[jt][2], SC[jt][3])));
            if (__any(mx > m_ + 8.0f)) {
                mx = fmaxf(mx, __shfl_xor(mx, 16));
                mx = fmaxf(mx, __shfl_xor(mx, 32));
                const float mn = fmaxf(m_, mx);
                const float alpha = __builtin_amdgcn_exp2f(m_ - mn);
                m_ = mn;
                l_ *= alpha;
#pragma unroll
                for (int dt = 0; dt < 4; ++dt) O[dt] *= alpha;
            }
            float sum = 0.0f;
#pragma unroll
            for (int jt = 0; jt < 4; ++jt)
#pragma unroll
                for (int r = 0; r < 4; ++r) {
                    const float pv = __builtin_amdgcn_exp2f(SC[jt][r] - m_);
                    SC[jt][r] = pv;
                    sum += pv;
                }
            l_ += sum;
            __builtin_amdgcn_s_setprio(1);
#pragma unroll
            for (int s = 0; s < 2; ++s) {
                bf16x8 Pf;
#pragma unroll
                for (int i = 0; i < 8; ++i)
                    Pf[i] = (__bf16)SC[2 * s + (i >> 2)][i & 3];
#pragma unroll
                for (int dt = 0; dt < 4; ++dt) {
                    const bf16x8 Vf = *reinterpret_cast<const bf16x8*>(
                        vb + (16 * dt + lr) * 64 + ((32 * s + 8 * lg) ^ xel));
                    O[dt] = __builtin_amdgcn_mfma_f32_16x16x32_bf16(Vf, Pf, O[dt], 0, 0, 0);
                }
            }
            __builtin_amdgcn_s_setprio(0);
        };

        f32x4 S0[4], S1[4];
        int t = 0;

        // prologue: stage tiles 0,1; S0 = QK(0)
        stage2(Ks[0], Vs[0]);
        stage2(Ks[1], Vs[1]);
        __syncthreads();
        qk_step(S0, Ks[0]);

        // main loop: 6 statically-indexed bodies per iteration (tiles t..t+5),
        // all guaranteed pre-diagonal (no mask) and fully staged/prefetched.
        for (; t + 8 <= nkt; t += 6) {
            stage2(Ks[2], Vs[2]); qk_step(S1, Ks[1]); smpv(S0, Vs[0], false); __syncthreads();
            stage2(Ks[0], Vs[0]); qk_step(S0, Ks[2]); smpv(S1, Vs[1], false); __syncthreads();
            stage2(Ks[1], Vs[1]); qk_step(S1, Ks[0]); smpv(S0, Vs[2], false); __syncthreads();
            stage2(Ks[2], Vs[2]); qk_step(S0, Ks[1]); smpv(S1, Vs[0], false); __syncthreads();
            stage2(Ks[0], Vs[0]); qk_step(S1, Ks[2]); smpv(S0, Vs[1], false); __syncthreads();
            stage2(Ks[1], Vs[1]); qk_step(S0, Ks[0]); smpv(S1, Vs[2], false); __syncthreads();
        }

        // tail: <=7 tiles, dynamic ring indices, mask on the last tile
        {
            f32x4 Sp[4];
#pragma unroll
            for (int jt = 0; jt < 4; ++jt) Sp[jt] = S0[jt];
            for (; t < nkt; ++t) {
                if (t + 2 < nkt) stage2(Ks[(t + 2) % 3], Vs[(t + 2) % 3]);
                f32x4 Sn[4];
                if (t + 1 < nkt) qk_step(Sn, Ks[(t + 1) % 3]);
                smpv(Sp, Vs[t % 3], t == nkt - 1);
                __syncthreads();
#pragma unroll
                for (int jt = 0; jt < 4; ++jt) Sp[jt] = Sn[jt];
            }
        }

        // epilogue: deferred row-sum of l, then O / l
        float lt = l_;
        lt += __shfl_xor(lt, 16);
        lt += __shfl_xor(lt, 32);
        const float inv = 1.0f / lt;
        __bf16* op = attn_out + ((size_t)b * 4096 + wq0 + lr) * 512 + h * 64;
#pragma unroll
        for (int dt = 0; dt < 4; ++dt) {
            union { __bf16 h4[4]; uint2 u; } ow;
#pragma unroll
            for (int r = 0; r < 4; ++r) ow.h4[r] = (__bf16)(O[dt][r] * inv);
            *reinterpret_cast<uint2*>(op + 16 * dt + 4 * lg) = ow.u;
        }
    }
}

// ---------------------------------------------------------------------------
extern "C" void kernel_launch(void* const* d_in, const int* in_sizes, int n_in,
                              void* d_out, int out_size, void* d_ws, size_t ws_size,
                              hipStream_t stream) {
    (void)in_sizes; (void)n_in; (void)out_size; (void)ws_size;
    const float* x    = (const float*)d_in[0];
    const float* rot  = (const float*)d_in[1];
    const float* rmsw = (const float*)d_in[2];
    const float* wqkv = (const float*)d_in[3];
    const float* wout = (const float*)d_in[4];
    float* out = (float*)d_out;

    char* ws = (char*)d_ws;
    __bf16* xn    = (__bf16*)ws;                       // 16,777,216 B
    __bf16* wqkvt = (__bf16*)(ws + 16777216);          //  3,145,728 B
    __bf16* woutt = (__bf16*)(ws + 16777216 + 3145728);//  1,048,576 B
    __bf16* aout  = (__bf16*)(ws + 16777216 + 3145728 + 1048576); // 8,388,608 B
    // d_out during pipeline: qk [0,16.78M), csin [16.78M,18.87M),
    // vt [18.87M,27.26M) — all dead before the final GEMM overwrites d_out.
    __bf16* qk   = (__bf16*)d_out;
    float2* csin = (float2*)((char*)d_out + 16777216);
    __bf16* vt   = (__bf16*)((char*)d_out + 18874368);

    rmsnorm_kernel<<<8192, 256, 0, stream>>>(x, rmsw, xn);
    transpose_cast_kernel<<<dim3(48, 32), dim3(32, 8), 0, stream>>>(wqkv, wqkvt, 1024, 1536);
    transpose_cast_kernel<<<dim3(32, 16), dim3(32, 8), 0, stream>>>(wout, woutt, 512, 1024);
    csin_kernel<<<1024, 256, 0, stream>>>(rot, csin);
    gemm_bt<__bf16, 1><<<dim3(12, 64), 256, 0, stream>>>(xn, wqkvt, qk, vt, 8192, 1536, 1024);
    rope_kernel<<<2048, 256, 0, stream>>>(qk, csin);
    attn_kernel<<<512, 256, 0, stream>>>(qk, vt, aout);
    gemm_bt<float, 0><<<dim3(8, 64), 256, 0, stream>>>(aout, woutt, out, nullptr, 8192, 1024, 512);
}

// Round 10
// 142.812 us; speedup vs baseline: 1.2353x; 1.0302x over previous
//
#include <hip/hip_runtime.h>
#include <hip/hip_bf16.h>
#include <cstdint>

using bf16x8 = __attribute__((ext_vector_type(8))) __bf16;
using f32x4  = __attribute__((ext_vector_type(4))) float;

#define LOG2E 1.4426950408889634f

__device__ inline void gload16(__bf16* lds, const __bf16* g) {
    __builtin_amdgcn_global_load_lds((const __attribute__((address_space(1))) void*)g,
                                     (__attribute__((address_space(3))) void*)lds, 16, 0, 0);
}
__device__ inline void wait_barrier4() {
    asm volatile("s_waitcnt vmcnt(4)" ::: "memory");
    __builtin_amdgcn_s_barrier();
}
__device__ inline void wait_barrier0() {
    asm volatile("s_waitcnt vmcnt(0)" ::: "memory");
    __builtin_amdgcn_s_barrier();
}

// ---------------------------------------------------------------------------
// RMSNorm: one block (256 threads) per row of 1024 fp32 -> bf16
// ---------------------------------------------------------------------------
__global__ __launch_bounds__(256) void rmsnorm_kernel(const float* __restrict__ x,
                                                      const float* __restrict__ w,
                                                      __bf16* __restrict__ xn) {
    const int row = blockIdx.x;
    const float4 v = reinterpret_cast<const float4*>(x + (size_t)row * 1024)[threadIdx.x];
    float ss = v.x * v.x + v.y * v.y + v.z * v.z + v.w * v.w;
#pragma unroll
    for (int i = 1; i < 64; i <<= 1) ss += __shfl_xor(ss, i);
    __shared__ float part[4];
    if ((threadIdx.x & 63) == 0) part[threadIdx.x >> 6] = ss;
    __syncthreads();
    const float total = part[0] + part[1] + part[2] + part[3];
    const float scale = rsqrtf(total * (1.0f / 1024.0f) + 1.1920929e-07f);
    const float4 wv = reinterpret_cast<const float4*>(w)[threadIdx.x];
    union { __bf16 h[4]; uint2 u; } pk;
    pk.h[0] = (__bf16)(v.x * scale * wv.x);
    pk.h[1] = (__bf16)(v.y * scale * wv.y);
    pk.h[2] = (__bf16)(v.z * scale * wv.z);
    pk.h[3] = (__bf16)(v.w * scale * wv.w);
    reinterpret_cast<uint2*>(xn + (size_t)row * 1024)[threadIdx.x] = pk.u;
}

// ---------------------------------------------------------------------------
// Transpose + cast: in (K x N) fp32 row-major -> out (N x K) bf16 row-major
// ---------------------------------------------------------------------------
__global__ void transpose_cast_kernel(const float* __restrict__ in,
                                      __bf16* __restrict__ out, int K, int N) {
    __shared__ float tile[32][33];
    const int n0 = blockIdx.x * 32, k0 = blockIdx.y * 32;
#pragma unroll
    for (int r = threadIdx.y; r < 32; r += 8)
        tile[r][threadIdx.x] = in[(size_t)(k0 + r) * N + n0 + threadIdx.x];
    __syncthreads();
#pragma unroll
    for (int r = threadIdx.y; r < 32; r += 8)
        out[(size_t)(n0 + r) * K + k0 + threadIdx.x] = (__bf16)tile[threadIdx.x][r];
}

// ---------------------------------------------------------------------------
// cos/sin table: csin[pos*64+d] = (cos, sin) of rot[pos][d]. 262144 entries.
// ---------------------------------------------------------------------------
__global__ __launch_bounds__(256) void csin_kernel(const float* __restrict__ rot,
                                                   float2* __restrict__ csin) {
    const int i = blockIdx.x * 256 + threadIdx.x;
    float s, c;
    sincosf(rot[i], &s, &c);
    csin[i] = make_float2(c, s);
}

// ---------------------------------------------------------------------------
// RoPE (table-based) in-place on qk [8192][1024]; q (cols<512) also scaled by
// d^-0.5 * log2(e). One wave per (b,pos): lane = h*8 + d-quad.
// ---------------------------------------------------------------------------
__global__ __launch_bounds__(256) void rope_kernel(__bf16* __restrict__ qk,
                                                   const float2* __restrict__ csin) {
    const int row = blockIdx.x * 4 + (threadIdx.x >> 6);   // b*4096+pos
    const int lane = threadIdx.x & 63;
    const int h = lane >> 3, dl = (lane & 7) * 4;
    const int pos = row & 4095;
    const float4 csA = *reinterpret_cast<const float4*>(&csin[pos * 64 + dl]);
    const float4 csB = *reinterpret_cast<const float4*>(&csin[pos * 64 + dl + 2]);
    const float4 csC = *reinterpret_cast<const float4*>(&csin[pos * 64 + dl + 32]);
    const float4 csD = *reinterpret_cast<const float4*>(&csin[pos * 64 + dl + 34]);
    const float c0[4] = {csA.x, csA.z, csB.x, csB.z};
    const float s0[4] = {csA.y, csA.w, csB.y, csB.w};
    const float c1[4] = {csC.x, csC.z, csD.x, csD.z};
    const float s1[4] = {csC.y, csC.w, csD.y, csD.w};
    __bf16* p = qk + (size_t)row * 1024 + h * 64 + dl;
    const float qs = 0.125f * LOG2E;
#pragma unroll
    for (int part = 0; part < 2; ++part) {      // q then k
        __bf16* pp = p + part * 512;
        const float sc = part ? 1.0f : qs;
        union { uint2 u; __bf16 hh[4]; } va, vb, oa, ob;
        va.u = *reinterpret_cast<const uint2*>(pp);
        vb.u = *reinterpret_cast<const uint2*>(pp + 32);
#pragma unroll
        for (int j = 0; j < 4; ++j) {
            const float a = (float)va.hh[j], b2 = (float)vb.hh[j];
            oa.hh[j] = (__bf16)((a * c0[j] - b2 * s0[j]) * sc);
            ob.hh[j] = (__bf16)((b2 * c1[j] + a * s1[j]) * sc);
        }
        *reinterpret_cast<uint2*>(pp)      = oa.u;
        *reinterpret_cast<uint2*>(pp + 32) = ob.u;
    }
}

// ---------------------------------------------------------------------------
// GEMM: C(MxN) = A(MxK) @ Bt(NxK)^T, bf16 in, fp32 accum.
// Ring-3 LDS, stage(k+2) issued before compute(k), ONE raw barrier per
// K-step with counted vmcnt(4) (T3/T4): prefetch loads stay in flight
// across barriers; only the last 2 steps drain.
// MODE 0: plain OutT output, ld = N.
// MODE 1 (QKV): cols <1024 -> qk buf [8192][1024]; v -> vt[1024][4096]
//   transposed + kappa-permuted (attention P stays in registers).
// ---------------------------------------------------------------------------
template <typename OutT, int MODE>
__global__ __launch_bounds__(256) void gemm_bt(const __bf16* __restrict__ A,
                                               const __bf16* __restrict__ Bt,
                                               OutT* __restrict__ C,
                                               __bf16* __restrict__ vt,
                                               int M, int N, int K) {
    __shared__ __align__(16) __bf16 As[3][128 * 32];
    __shared__ __align__(16) __bf16 Bs[3][128 * 32];
    const int bm = blockIdx.y, bn = blockIdx.x;
    const int tid = threadIdx.x;
    const int w = tid >> 6, l = tid & 63, lg = l >> 4, lr = l & 15;
    const int wr = w >> 1, wc = w & 1;
    const __bf16* Ab = A + (size_t)(bm * 128) * K;
    const __bf16* Bb = Bt + (size_t)(bn * 128) * K;
    const int srow = tid >> 2, scol = (tid & 3) * 8;
    const __bf16* Asrc = Ab + (size_t)srow * K + scol;
    const __bf16* Bsrc = Bb + (size_t)srow * K + scol;

    auto stage = [&](int k2) {
        const int nx = k2 % 3;
        const int off = k2 * 32;
        gload16(&As[nx][tid * 8],        Asrc + off);
        gload16(&As[nx][2048 + tid * 8], Asrc + (size_t)64 * K + off);
        gload16(&Bs[nx][tid * 8],        Bsrc + off);
        gload16(&Bs[nx][2048 + tid * 8], Bsrc + (size_t)64 * K + off);
    };

    const int NS = K >> 5;
    f32x4 acc[4][4] = {};
    stage(0);
    stage(1);
    wait_barrier4();                      // tile 0 landed (tile 1 may fly)
    for (int k = 0; k < NS; ++k) {
        const bool more = (k + 2 < NS);
        if (more) stage(k + 2);
        const __bf16* Ac = &As[k % 3][0];
        const __bf16* Bc = &Bs[k % 3][0];
        bf16x8 af[4], bfr[4];
#pragma unroll
        for (int m = 0; m < 4; ++m)
            af[m] = *reinterpret_cast<const bf16x8*>(Ac + (wr * 64 + m * 16 + lr) * 32 + lg * 8);
#pragma unroll
        for (int nn = 0; nn < 4; ++nn)
            bfr[nn] = *reinterpret_cast<const bf16x8*>(Bc + (wc * 64 + nn * 16 + lr) * 32 + lg * 8);
#pragma unroll
        for (int m = 0; m < 4; ++m)
#pragma unroll
            for (int nn = 0; nn < 4; ++nn)
                acc[m][nn] = __builtin_amdgcn_mfma_f32_16x16x32_bf16(af[m], bfr[nn],
                                                                     acc[m][nn], 0, 0, 0);
        if (more) wait_barrier4();        // newest 4 (tile k+2) stay in flight
        else      wait_barrier0();        // tail: drain
    }
    if constexpr (MODE == 1) {
        const int cb = bn * 128 + wc * 64;
        if (cb < 1024) {                          // q,k -> qk buf (ld 1024)
#pragma unroll
            for (int m = 0; m < 4; ++m) {
                const int rg = bm * 128 + wr * 64 + m * 16 + 4 * lg;
#pragma unroll
                for (int nn = 0; nn < 4; ++nn) {
                    const int cg = cb + nn * 16 + lr;
#pragma unroll
                    for (int r = 0; r < 4; ++r)
                        C[(size_t)(rg + r) * 1024 + cg] = (OutT)acc[m][nn][r];
                }
            }
        } else {                                  // v -> vt transposed + kappa
#pragma unroll
            for (int m = 0; m < 4; ++m) {
                const int rg = bm * 128 + wr * 64 + m * 16 + 4 * lg;
                const int bidx = rg >> 12, pos0 = rg & 4095;
                const int a0 = pos0 & 63;
                const int cp = 32 * (a0 >> 5) + 8 * ((a0 >> 2) & 3) + 4 * ((a0 >> 4) & 1);
                const int nbase = (pos0 & ~63) + cp;
#pragma unroll
                for (int nn = 0; nn < 4; ++nn) {
                    const int col = cb + nn * 16 + lr - 1024;
                    const int hh = col >> 6, dd = col & 63;
                    union { __bf16 h4[4]; uint2 u; } pk2;
#pragma unroll
                    for (int r = 0; r < 4; ++r) pk2.h4[r] = (__bf16)acc[m][nn][r];
                    *reinterpret_cast<uint2*>(&vt[((size_t)(bidx * 8 + hh) * 64 + dd) * 4096 + nbase]) = pk2.u;
                }
            }
        }
        return;
    }
#pragma unroll
    for (int m = 0; m < 4; ++m) {
        const int rg = bm * 128 + wr * 64 + m * 16 + 4 * lg;
#pragma unroll
        for (int nn = 0; nn < 4; ++nn) {
            const int cg = bn * 128 + wc * 64 + nn * 16 + lr;
#pragma unroll
            for (int r = 0; r < 4; ++r)
                C[(size_t)(rg + r) * N + cg] = (OutT)acc[m][nn][r];
        }
    }
}

// ---------------------------------------------------------------------------
// Causal flash attention v10: ring-4 K/V buffers + counted vmcnt(4) with raw
// s_barrier (T4): the per-tile staging loads are issued 3 tiles ahead and
// NEVER drained in the main loop (wait leaves the newest 4 vmem ops in
// flight; tile t+2 is guaranteed landed for next iter's QK read).
// Zero-VALU staging (global_load_lds, pre-swizzled source), P in registers
// (kappa-permuted vt), deferred reductions, defer-max, unroll x4 static.
// 512 blocks x 256 thr, q-tile pair {p, 63-p} per block, 2 blocks/CU.
// ---------------------------------------------------------------------------
__global__ __launch_bounds__(256) void attn_kernel(const __bf16* __restrict__ qkp,
                                                   const __bf16* __restrict__ vt,
                                                   __bf16* __restrict__ attn_out) {
    const int bid = blockIdx.x;                      // 512 blocks
    const int swz = (bid & 7) * 64 + (bid >> 3);     // XCD-major
    const int bh  = swz >> 5;                        // 2 heads per XCD
    const int p   = swz & 31;                        // pair id 0..31
    const int b = bh >> 3, h = bh & 7;
    const int tid = threadIdx.x;
    const int w = tid >> 6, l = tid & 63, lg = l >> 4, lr = l & 15;

    __shared__ __align__(16) __bf16 Ks[4][64 * 64];
    __shared__ __align__(16) __bf16 Vs[4][64 * 64];

    const __bf16* qbase = qkp + (size_t)b * 4096 * 1024 + h * 64;
    const __bf16* kbase = qbase + 512;
    const __bf16* vtb   = vt + (size_t)(b * 8 + h) * 64 * 4096;

    // staging: chunk tid -> (row = tid>>3, col8 = tid&7); source col8 swizzled
    const int sr = tid >> 3;
    const int sc = ((tid & 7) ^ (sr & 7)) * 8;
    const __bf16* ksrc0 = kbase + (size_t)sr * 1024 + sc;
    const __bf16* vsrc0 = vtb + (size_t)sr * 4096 + sc;

    const int xel = (lr & 7) * 8;                    // read-side swizzle

    for (int seg = 0; seg < 2; ++seg) {
        const int qt = seg ? (63 - p) : p;
        const int wq0 = qt * 64 + 16 * w;
        const int nkt = qt + 1;

        bf16x8 Qf[2];
#pragma unroll
        for (int kh = 0; kh < 2; ++kh)
            Qf[kh] = *reinterpret_cast<const bf16x8*>(
                qbase + (size_t)(wq0 + lr) * 1024 + 32 * kh + 8 * lg);

        f32x4 O[4] = {};
        float m_ = -1e30f, l_ = 0.0f;
        const __bf16* kp = ksrc0;        // advances 64*1024 per staged tile
        const __bf16* vp = vsrc0;        // advances 64 per staged tile

        auto stage2 = [&](__bf16* kdst, __bf16* vdst) {
            gload16(kdst + tid * 8,         kp);
            gload16(kdst + (tid + 256) * 8, kp + 32 * 1024);
            gload16(vdst + tid * 8,         vp);
            gload16(vdst + (tid + 256) * 8, vp + 32 * 4096);
            kp += 64 * 1024;
            vp += 64;
        };
        auto qk_step = [&](f32x4 (&S)[4], const __bf16* kb) {
            __builtin_amdgcn_s_setprio(1);
#pragma unroll
            for (int jt = 0; jt < 4; ++jt) {
                const __bf16* kr = kb + (16 * jt + lr) * 64;
                const bf16x8 Kf0 = *reinterpret_cast<const bf16x8*>(kr + ((8 * lg) ^ xel));
                const bf16x8 Kf1 = *reinterpret_cast<const bf16x8*>(kr + ((32 + 8 * lg) ^ xel));
                f32x4 z = {};
                z = __builtin_amdgcn_mfma_f32_16x16x32_bf16(Kf0, Qf[0], z, 0, 0, 0);
                S[jt] = __builtin_amdgcn_mfma_f32_16x16x32_bf16(Kf1, Qf[1], z, 0, 0, 0);
            }
            __builtin_amdgcn_s_setprio(0);
        };
        auto smpv = [&](f32x4 (&SC)[4], const __bf16* vb, bool domask) {
            if (domask) {
#pragma unroll
                for (int jt = 0; jt < 4; ++jt)
#pragma unroll
                    for (int r = 0; r < 4; ++r)
                        if (16 * jt + 4 * lg + r > 16 * w + lr) SC[jt][r] = -1e30f;
            }
            float mx = -1e30f;
#pragma unroll
            for (int jt = 0; jt < 4; ++jt)
                mx = fmaxf(mx, fmaxf(fmaxf(SC[jt][0], SC[jt][1]), fmaxf(SC[jt][2], SC[jt][3])));
            if (__any(mx > m_ + 8.0f)) {
                mx = fmaxf(mx, __shfl_xor(mx, 16));
                mx = fmaxf(mx, __shfl_xor(mx, 32));
                const float mn = fmaxf(m_, mx);
                const float alpha = __builtin_amdgcn_exp2f(m_ - mn);
                m_ = mn;
                l_ *= alpha;
#pragma unroll
                for (int dt = 0; dt < 4; ++dt) O[dt] *= alpha;
            }
            float sum = 0.0f;
#pragma unroll
            for (int jt = 0; jt < 4; ++jt)
#pragma unroll
                for (int r = 0; r < 4; ++r) {
                    const float pv = __builtin_amdgcn_exp2f(SC[jt][r] - m_);
                    SC[jt][r] = pv;
                    sum += pv;
                }
            l_ += sum;
            __builtin_amdgcn_s_setprio(1);
#pragma unroll
            for (int s = 0; s < 2; ++s) {
                bf16x8 Pf;
#pragma unroll
                for (int i = 0; i < 8; ++i)
                    Pf[i] = (__bf16)SC[2 * s + (i >> 2)][i & 3];
#pragma unroll
                for (int dt = 0; dt < 4; ++dt) {
                    const bf16x8 Vf = *reinterpret_cast<const bf16x8*>(
                        vb + (16 * dt + lr) * 64 + ((32 * s + 8 * lg) ^ xel));
                    O[dt] = __builtin_amdgcn_mfma_f32_16x16x32_bf16(Vf, Pf, O[dt], 0, 0, 0);
                }
            }
            __builtin_amdgcn_s_setprio(0);
        };

        f32x4 S0[4], S1[4];
        int t = 0;

        // prologue: stage tiles 0,1,2 (ring slots 0,1,2); tiles 0,1 landed
        stage2(Ks[0], Vs[0]);
        stage2(Ks[1], Vs[1]);
        stage2(Ks[2], Vs[2]);
        wait_barrier4();                 // leaves tile-2 loads in flight
        qk_step(S0, Ks[0]);

        // main loop: 4 statically-indexed bodies (ring-4 x S-parity-2),
        // all pre-diagonal, stage always valid, counted vmcnt(4) barriers.
        for (; t + 8 <= nkt; t += 4) {
            stage2(Ks[3], Vs[3]); qk_step(S1, Ks[1]); smpv(S0, Vs[0], false); wait_barrier4();
            stage2(Ks[0], Vs[0]); qk_step(S0, Ks[2]); smpv(S1, Vs[1], false); wait_barrier4();
            stage2(Ks[1], Vs[1]); qk_step(S1, Ks[3]); smpv(S0, Vs[2], false); wait_barrier4();
            stage2(Ks[2], Vs[2]); qk_step(S0, Ks[0]); smpv(S1, Vs[3], false); wait_barrier4();
        }

        // tail: <=7 tiles, dynamic ring indices (&3), mask on the last tile
        {
            f32x4 Sp[4];
#pragma unroll
            for (int jt = 0; jt < 4; ++jt) Sp[jt] = S0[jt];
            for (; t < nkt; ++t) {
                const bool more3 = (t + 3 < nkt);
                if (more3) stage2(Ks[(t + 3) & 3], Vs[(t + 3) & 3]);
                f32x4 Sn[4];
                if (t + 1 < nkt) qk_step(Sn, Ks[(t + 1) & 3]);
                smpv(Sp, Vs[t & 3], t == nkt - 1);
                if (more3) wait_barrier4();
                else       wait_barrier0();
#pragma unroll
                for (int jt = 0; jt < 4; ++jt) Sp[jt] = Sn[jt];
            }
        }

        // epilogue: deferred row-sum of l, then O / l
        float lt = l_;
        lt += __shfl_xor(lt, 16);
        lt += __shfl_xor(lt, 32);
        const float inv = 1.0f / lt;
        __bf16* op = attn_out + ((size_t)b * 4096 + wq0 + lr) * 512 + h * 64;
#pragma unroll
        for (int dt = 0; dt < 4; ++dt) {
            union { __bf16 h4[4]; uint2 u; } ow;
#pragma unroll
            for (int r = 0; r < 4; ++r) ow.h4[r] = (__bf16)(O[dt][r] * inv);
            *reinterpret_cast<uint2*>(op + 16 * dt + 4 * lg) = ow.u;
        }
    }
}

// ---------------------------------------------------------------------------
extern "C" void kernel_launch(void* const* d_in, const int* in_sizes, int n_in,
                              void* d_out, int out_size, void* d_ws, size_t ws_size,
                              hipStream_t stream) {
    (void)in_sizes; (void)n_in; (void)out_size; (void)ws_size;
    const float* x    = (const float*)d_in[0];
    const float* rot  = (const float*)d_in[1];
    const float* rmsw = (const float*)d_in[2];
    const float* wqkv = (const float*)d_in[3];
    const float* wout = (const float*)d_in[4];
    float* out = (float*)d_out;

    char* ws = (char*)d_ws;
    __bf16* xn    = (__bf16*)ws;                       // 16,777,216 B
    __bf16* wqkvt = (__bf16*)(ws + 16777216);          //  3,145,728 B
    __bf16* woutt = (__bf16*)(ws + 16777216 + 3145728);//  1,048,576 B
    __bf16* aout  = (__bf16*)(ws + 16777216 + 3145728 + 1048576); // 8,388,608 B
    // d_out during pipeline: qk [0,16.78M), csin [16.78M,18.87M),
    // vt [18.87M,27.26M) — all dead before the final GEMM overwrites d_out.
    __bf16* qk   = (__bf16*)d_out;
    float2* csin = (float2*)((char*)d_out + 16777216);
    __bf16* vt   = (__bf16*)((char*)d_out + 18874368);

    rmsnorm_kernel<<<8192, 256, 0, stream>>>(x, rmsw, xn);
    transpose_cast_kernel<<<dim3(48, 32), dim3(32, 8), 0, stream>>>(wqkv, wqkvt, 1024, 1536);
    transpose_cast_kernel<<<dim3(32, 16), dim3(32, 8), 0, stream>>>(wout, woutt, 512, 1024);
    csin_kernel<<<1024, 256, 0, stream>>>(rot, csin);
    gemm_bt<__bf16, 1><<<dim3(12, 64), 256, 0, stream>>>(xn, wqkvt, qk, vt, 8192, 1536, 1024);
    rope_kernel<<<2048, 256, 0, stream>>>(qk, csin);
    attn_kernel<<<512, 256, 0, stream>>>(qk, vt, aout);
    gemm_bt<float, 0><<<dim3(8, 64), 256, 0, stream>>>(aout, woutt, out, nullptr, 8192, 1024, 512);
}